// Round 1
// baseline (1257.193 us; speedup 1.0000x reference)
//
#include <hip/hip_runtime.h>

// Grid constants (padded 66^3)
#define GD   66
#define GHW  (66*66)
#define GDHW (66*66*66)
#define CI   32
#define CO   32

__device__ __forceinline__ void atomAdd(float* p, float v) {
    // native global_atomic_add_f32 on gfx950
    unsafeAtomicAdd(p, v);
}

// Particle-to-grid scatter, offset-group-outer / K-register-resident.
// Loop t over 9 (oi,oj) groups; K[t][ok=0..2][ci][co] lives in 96 VGPRs and is
// reused across ALL particles (the old scheme re-read K from LDS per particle:
// 86.4M ds_read_b32 ~= 815us of CU-serialized LDS issue -- the bottleneck).
// CELLCO=true : dst layout [b][cell][co]  (co contiguous -> 1-2 cachelines per atomic)
// CELLCO=false: dst layout [b][co][cell]  (direct output layout fallback)
template<bool CELLCO>
__global__ __launch_bounds__(256) void p2g_kernel(
    const float* __restrict__ x, const float* __restrict__ pos,
    const float* __restrict__ kern, const float* __restrict__ bias,
    float* __restrict__ dst, int N, int nPairs)
{
    const int co   = threadIdx.x & 31;
    const int half = threadIdx.x >> 5;       // 0..7 half-waves per block
    const float bco = bias[co];
    const int halvesTotal = gridDim.x * 8;

    for (int t = 0; t < 9; ++t) {            // t = oi*3 + oj
        const int oi = t / 3, oj = t - 3*oi;

        // K columns for the 3 ok-offsets of this (oi,oj): register-resident.
        // 96 coalesced 128B-line loads per wave per group (L2-hit after first wave).
        float kreg[3][32];
        #pragma unroll
        for (int ok = 0; ok < 3; ++ok) {
            const float* kp = kern + (size_t)(t*3 + ok)*1024 + co;
            #pragma unroll
            for (int ci = 0; ci < 32; ++ci)
                kreg[ok][ci] = kp[ci*32];
        }

        for (int pp = blockIdx.x*8 + half; pp < nPairs; pp += halvesTotal) {
            const int g0 = pp*2;             // two particles per half-wave

            // x for both particles, register-resident (broadcast float4 loads)
            float xr[2][32];
            #pragma unroll
            for (int p = 0; p < 2; ++p) {
                const float4* xp = (const float4*)(x + (size_t)(g0+p)*CI);
                #pragma unroll
                for (int i = 0; i < 8; ++i) {
                    float4 v = xp[i];
                    xr[p][4*i+0]=v.x; xr[p][4*i+1]=v.y; xr[p][4*i+2]=v.z; xr[p][4*i+3]=v.w;
                }
            }

            // weights for this (oi,oj) group + base cell
            float wxy[2], wz[2][3];
            int cb[2], bsel[2];
            #pragma unroll
            for (int p = 0; p < 2; ++p) {
                const int gp = g0 + p;
                float px = pos[gp*3+0]*64.f, py = pos[gp*3+1]*64.f, pz = pos[gp*3+2]*64.f;
                int bx = (int)px, by = (int)py, bz = (int)pz;
                float fx = px - bx - 0.5f, fy = py - by - 0.5f, fz = pz - bz - 0.5f;
                float wx = (oi==0) ? 0.5f*(0.5f-fx)*(0.5f-fx)
                         : (oi==1) ? 0.75f - fx*fx
                                   : 0.5f*(0.5f+fx)*(0.5f+fx);
                float wy = (oj==0) ? 0.5f*(0.5f-fy)*(0.5f-fy)
                         : (oj==1) ? 0.75f - fy*fy
                                   : 0.5f*(0.5f+fy)*(0.5f+fy);
                wxy[p] = wx*wy;
                wz[p][0]=0.5f*(0.5f-fz)*(0.5f-fz); wz[p][1]=0.75f-fz*fz; wz[p][2]=0.5f*(0.5f+fz)*(0.5f+fz);
                cb[p]   = (bx+oi)*GHW + (by+oj)*GD + bz;  // cell for ok=0
                bsel[p] = (gp >= N) ? 1 : 0;              // batch
            }

            // 3 offsets x 2 particles x 32 ci, all from registers: 192 FMAs, 0 LDS ops
            float y[3][2];
            #pragma unroll
            for (int ok = 0; ok < 3; ++ok) { y[ok][0] = bco; y[ok][1] = bco; }
            #pragma unroll
            for (int ci = 0; ci < 32; ++ci) {
                float x0 = xr[0][ci], x1 = xr[1][ci];
                #pragma unroll
                for (int ok = 0; ok < 3; ++ok) {
                    float kv = kreg[ok][ci];
                    y[ok][0] += x0*kv;
                    y[ok][1] += x1*kv;
                }
            }

            // scatter: 3 adjacent cell rows per particle (contiguous 128B lines in CELLCO)
            #pragma unroll
            for (int ok = 0; ok < 3; ++ok) {
                {
                    int cell = cb[0] + ok;
                    size_t a = CELLCO ? (((size_t)bsel[0]*GDHW + cell)*32 + (size_t)co)
                                      : (((size_t)(bsel[0]*32 + co))*GDHW + (size_t)cell);
                    atomAdd(dst + a, wxy[0]*wz[0][ok]*y[ok][0]);
                }
                {
                    int cell = cb[1] + ok;
                    size_t a = CELLCO ? (((size_t)bsel[1]*GDHW + cell)*32 + (size_t)co)
                                      : (((size_t)(bsel[1]*32 + co))*GDHW + (size_t)cell);
                    atomAdd(dst + a, wxy[1]*wz[1][ok]*y[ok][1]);
                }
            }
        }
    }
}

// Transpose ws[b][cell][co] -> out[b][co][cell], tiled 32x32 through LDS.
__global__ __launch_bounds__(256) void transp_kernel(
    const float* __restrict__ ws, float* __restrict__ out)
{
    __shared__ float tile[32][33];
    const int b     = blockIdx.y;
    const int cell0 = blockIdx.x * 32;
    const int n     = min(32, GDHW - cell0);

    const float* src = ws + ((size_t)b*GDHW + cell0)*32;
    for (int e = threadIdx.x; e < n*32; e += 256)
        tile[e>>5][e&31] = src[e];          // coalesced read, row write (no conflict)
    __syncthreads();
    for (int e = threadIdx.x; e < 32*32; e += 256) {
        int c  = e >> 5;    // co
        int cl = e & 31;    // cell within tile
        if (cl < n)
            out[((size_t)(b*32 + c))*GDHW + cell0 + cl] = tile[cl][c];  // coalesced write, col read stride 33
    }
}

extern "C" void kernel_launch(void* const* d_in, const int* in_sizes, int n_in,
                              void* d_out, int out_size, void* d_ws, size_t ws_size,
                              hipStream_t stream) {
    const float* x    = (const float*)d_in[0];
    const float* pos  = (const float*)d_in[1];
    const float* kern = (const float*)d_in[2];
    const float* bias = (const float*)d_in[3];
    float* out = (float*)d_out;

    const int N  = in_sizes[0] / (2*CI);   // B*N*Ci / (B*Ci)
    const int BN = 2*N;
    const int nPairs = (BN + 1) / 2;

    const size_t wsNeed = (size_t)2 * GDHW * CO * sizeof(float);  // 73.6 MB

    if (ws_size >= wsNeed) {
        float* ws = (float*)d_ws;
        hipMemsetAsync(ws, 0, wsNeed, stream);
        p2g_kernel<true><<<dim3(2048), dim3(256), 0, stream>>>(x, pos, kern, bias, ws, N, nPairs);
        transp_kernel<<<dim3((GDHW + 31)/32, 2), dim3(256), 0, stream>>>(ws, out);
    } else {
        hipMemsetAsync(out, 0, (size_t)out_size * sizeof(float), stream);
        p2g_kernel<false><<<dim3(2048), dim3(256), 0, stream>>>(x, pos, kern, bias, out, N, nPairs);
    }
}